// Round 11
// baseline (536.732 us; speedup 1.0000x reference)
//
#include <hip/hip_runtime.h>
#include <stdint.h>

typedef unsigned short u16;
typedef unsigned int   u32;
typedef __attribute__((ext_vector_type(8))) short bf16x8;
typedef __attribute__((ext_vector_type(4))) float f32x4;
typedef __attribute__((ext_vector_type(4))) u32   u32x4;
typedef __attribute__((ext_vector_type(2))) u32   u32x2;

// Problem constants
#define BB 4
#define SS 2048
#define DD 1024
#define HH 16
// DK = DV = 64
// fold 1/sqrt(DK) * log2(e) into Q so attn softmax uses exp2 directly
#define QSCALE 0.18033688011112042f

__device__ __forceinline__ u16 f2b(float f){
  u32 u = __builtin_bit_cast(u32, f);
  u32 r = (u + 0x7FFFu + ((u >> 16) & 1u)) >> 16;   // RNE bf16 (finite values only)
  return (u16)r;
}
__device__ __forceinline__ float b2f(u16 h){
  return __builtin_bit_cast(float, (u32)h << 16);
}
__device__ __forceinline__ u32 cvtpk(float lo, float hi){
  u32 r; asm("v_cvt_pk_bf16_f32 %0, %1, %2" : "=v"(r) : "v"(lo), "v"(hi)); return r;
}

// async global->LDS, 16B per lane; lds base must be wave-uniform + lane*16.
__device__ __forceinline__ void gload16(const u16* g, u16* l){
  __builtin_amdgcn_global_load_lds(
      (const __attribute__((address_space(1))) void*)(uintptr_t)g,
      (__attribute__((address_space(3))) void*)(uintptr_t)l,
      16, 0, 0);
}

// ---------------- f32 -> bf16 bulk convert, 3 tensors in one launch -----------------
__global__ __launch_bounds__(256)
void cvt_bf16_3(const float* __restrict__ q, const float* __restrict__ k,
                const float* __restrict__ v, u16* __restrict__ qo,
                u16* __restrict__ ko, u16* __restrict__ vo, int npack)
{
  const float* in = blockIdx.y == 0 ? q : (blockIdx.y == 1 ? k : v);
  u16* out        = blockIdx.y == 0 ? qo : (blockIdx.y == 1 ? ko : vo);
  for(int i = blockIdx.x * 256 + threadIdx.x; i < npack; i += gridDim.x * 256){
    const float4* p = (const float4*)in + 2 * (size_t)i;
    float4 a = p[0], b = p[1];
    u32x4 o;
    o.x = f2b(a.x) | ((u32)f2b(a.y) << 16);
    o.y = f2b(a.z) | ((u32)f2b(a.w) << 16);
    o.z = f2b(b.x) | ((u32)f2b(b.y) << 16);
    o.w = f2b(b.z) | ((u32)f2b(b.w) << 16);
    ((u32x4*)out)[i] = o;
  }
}

// ---------------- weight transpose + bf16 convert, 64x64 tiles, full-line stores ----
__global__ __launch_bounds__(256)
void transpose_cvt4(const float* __restrict__ W0, const float* __restrict__ W1,
                    const float* __restrict__ W2, const float* __restrict__ W3,
                    u16* __restrict__ T0, u16* __restrict__ T1,
                    u16* __restrict__ T2, u16* __restrict__ T3)
{
  const float* W = blockIdx.z == 0 ? W0 : (blockIdx.z == 1 ? W1 : (blockIdx.z == 2 ? W2 : W3));
  u16*        Wt = blockIdx.z == 0 ? T0 : (blockIdx.z == 1 ? T1 : (blockIdx.z == 2 ? T2 : T3));
  __shared__ float tile[64][65];
  const int tid = threadIdx.x;
  const int n0 = blockIdx.x * 64, k0 = blockIdx.y * 64;
  const int lr = tid >> 4, lc = tid & 15;
  #pragma unroll
  for(int i = 0; i < 4; ++i){
    float4 v = *(const float4*)(W + (size_t)(k0 + lr + 16*i) * DD + n0 + lc * 4);
    tile[lr + 16*i][lc*4 + 0] = v.x;
    tile[lr + 16*i][lc*4 + 1] = v.y;
    tile[lr + 16*i][lc*4 + 2] = v.z;
    tile[lr + 16*i][lc*4 + 3] = v.w;
  }
  __syncthreads();
  #pragma unroll
  for(int j = 0; j < 2; ++j){
    int idx = j * 256 + tid;
    int row = idx >> 3, seg = idx & 7;
    u32x4 o;
    o.x = f2b(tile[seg*8+0][row]) | ((u32)f2b(tile[seg*8+1][row]) << 16);
    o.y = f2b(tile[seg*8+2][row]) | ((u32)f2b(tile[seg*8+3][row]) << 16);
    o.z = f2b(tile[seg*8+4][row]) | ((u32)f2b(tile[seg*8+5][row]) << 16);
    o.w = f2b(tile[seg*8+6][row]) | ((u32)f2b(tile[seg*8+7][row]) << 16);
    *(u32x4*)(Wt + (size_t)(n0 + row) * DD + k0 + seg * 8) = o;
  }
}

// ---------------- merged QKV GEMM (blockIdx.z = mode), full-line LDS epilogue -------
__global__ __launch_bounds__(256)
void gemm_qkv(const u16* __restrict__ qA, const u16* __restrict__ kA, const u16* __restrict__ vA,
              const u16* __restrict__ BtQ, const u16* __restrict__ BtK, const u16* __restrict__ BtV,
              const float* __restrict__ bq, const float* __restrict__ bk, const float* __restrict__ bv,
              u16* __restrict__ Qo, u16* __restrict__ Ko, u16* __restrict__ Vo)
{
  const int mode = blockIdx.z;
  const u16* A   = mode == 0 ? qA  : (mode == 1 ? kA  : vA);
  const u16* Bt  = mode == 0 ? BtQ : (mode == 1 ? BtK : BtV);
  const float* bias = mode == 0 ? bq : (mode == 1 ? bk : bv);
  u16* Cout      = mode == 0 ? Qo  : (mode == 1 ? Ko  : Vo);

  __shared__ __align__(16) u16 smem[16384];
  u16* As = smem;
  u16* Bs = smem + 128*32;
  const int tid = threadIdx.x;
  const int w = tid >> 6, ln = tid & 63, g = ln >> 4, c16 = ln & 15;
  const int m0 = blockIdx.y * 128, n0 = blockIdx.x * 128;
  const int wr = (w >> 1) * 64, wc = (w & 1) * 64;

  f32x4 acc[4][4] = {};

  for(int kt = 0; kt < 1024; kt += 32){
    __syncthreads();
    {
      const int f0 = w * 2;
      #pragma unroll
      for(int j = 0; j < 2; ++j){
        int e = ((f0 + j) * 64 + ln) * 8;
        gload16(Bt + (size_t)(n0 + (e >> 5)) * 1024 + kt + (e & 31),
                Bs + (size_t)(f0 + j) * 512);
        gload16(A + (size_t)(m0 + (e >> 5)) * 1024 + kt + (e & 31),
                As + (size_t)(f0 + j) * 512);
      }
    }
    __syncthreads();
    bf16x8 a[4], b[4];
    #pragma unroll
    for(int mi = 0; mi < 4; ++mi)
      a[mi] = *(const bf16x8*)(As + (wr + mi*16 + c16) * 32 + g * 8);
    #pragma unroll
    for(int ni = 0; ni < 4; ++ni)
      b[ni] = *(const bf16x8*)(Bs + (wc + ni*16 + c16) * 32 + g * 8);
    #pragma unroll
    for(int mi = 0; mi < 4; ++mi)
      #pragma unroll
      for(int ni = 0; ni < 4; ++ni)
        acc[mi][ni] = __builtin_amdgcn_mfma_f32_16x16x32_bf16(a[mi], b[ni], acc[mi][ni], 0, 0, 0);
  }
  __syncthreads();

  char* st = (char*)smem + w * 8192;
  const float sc = (mode == 0) ? QSCALE : 1.f;
  const int bb = m0 >> 11;
  const int h  = (n0 + wc) >> 6;
  const int sbase = (m0 + wr) & 2047;

  if(mode < 2){
    #pragma unroll
    for(int ni = 0; ni < 4; ++ni){
      const float bvv = bias[n0 + wc + ni*16 + c16];
      const int gr = ni*2 + (c16 >> 3);
      const int within = (c16 & 7) * 2;
      #pragma unroll
      for(int mi = 0; mi < 4; ++mi)
        #pragma unroll
        for(int e = 0; e < 4; ++e){
          const int row = mi*16 + g*4 + e;
          *(u16*)(st + row*128 + ((gr ^ (row & 7)) << 4) + within)
              = f2b((acc[mi][ni][e] + bvv) * sc);
        }
    }
    asm volatile("s_waitcnt lgkmcnt(0)" ::: "memory");
    const int r8 = ln >> 3, jl = ln & 7;
    #pragma unroll
    for(int ii = 0; ii < 8; ++ii){
      const int row = ii*8 + r8;
      u16* dst = Cout + (((size_t)(bb*HH + h) * SS) + sbase + row) * 64 + jl*8;
      *(u32x4*)dst = *(const u32x4*)(st + row*128 + ((jl ^ (row & 7)) << 4));
    }
  } else {
    #pragma unroll
    for(int ni = 0; ni < 4; ++ni){
      const float bvv = bias[n0 + wc + ni*16 + c16];
      const int row = ni*16 + c16;
      #pragma unroll
      for(int mi = 0; mi < 4; ++mi)
        #pragma unroll
        for(int e = 0; e < 4; ++e){
          const int sl = mi*16 + g*4 + e;
          const int gr = sl >> 3;
          *(u16*)(st + row*128 + ((gr ^ (row & 7)) << 4) + (sl & 7) * 2)
              = f2b(acc[mi][ni][e] + bvv);
        }
    }
    asm volatile("s_waitcnt lgkmcnt(0)" ::: "memory");
    const int r8 = ln >> 3, jl = ln & 7;
    #pragma unroll
    for(int ii = 0; ii < 8; ++ii){
      const int d = ii*8 + r8;
      u16* dst = Cout + ((size_t)(bb*HH + h) * 64 + (n0 + wc - ((n0+wc)>>6<<6)) + d) * SS + sbase + jl*8;
      *(u32x4*)dst = *(const u32x4*)(st + d*128 + ((jl ^ (d & 7)) << 4));
    }
  }
}

// ---------------- out-proj GEMM -> bf16 tmp, full-line LDS epilogue -----------------
__global__ __launch_bounds__(256)
void gemm_o(const u16* __restrict__ A, const u16* __restrict__ Bt,
            const float* __restrict__ bias, u16* __restrict__ Cout)
{
  __shared__ __align__(16) u16 smem[16384];
  u16* As = smem;
  u16* Bs = smem + 128*32;
  const int tid = threadIdx.x;
  const int w = tid >> 6, ln = tid & 63, g = ln >> 4, c16 = ln & 15;
  const int m0 = blockIdx.y * 128, n0 = blockIdx.x * 128;
  const int wr = (w >> 1) * 64, wc = (w & 1) * 64;

  f32x4 acc[4][4] = {};

  for(int kt = 0; kt < 1024; kt += 32){
    __syncthreads();
    {
      const int f0 = w * 2;
      #pragma unroll
      for(int j = 0; j < 2; ++j){
        int e = ((f0 + j) * 64 + ln) * 8;
        gload16(Bt + (size_t)(n0 + (e >> 5)) * 1024 + kt + (e & 31),
                Bs + (size_t)(f0 + j) * 512);
        gload16(A + (size_t)(m0 + (e >> 5)) * 1024 + kt + (e & 31),
                As + (size_t)(f0 + j) * 512);
      }
    }
    __syncthreads();
    bf16x8 a[4], b[4];
    #pragma unroll
    for(int mi = 0; mi < 4; ++mi)
      a[mi] = *(const bf16x8*)(As + (wr + mi*16 + c16) * 32 + g * 8);
    #pragma unroll
    for(int ni = 0; ni < 4; ++ni)
      b[ni] = *(const bf16x8*)(Bs + (wc + ni*16 + c16) * 32 + g * 8);
    #pragma unroll
    for(int mi = 0; mi < 4; ++mi)
      #pragma unroll
      for(int ni = 0; ni < 4; ++ni)
        acc[mi][ni] = __builtin_amdgcn_mfma_f32_16x16x32_bf16(a[mi], b[ni], acc[mi][ni], 0, 0, 0);
  }
  __syncthreads();

  char* st = (char*)smem + w * 8192;
  #pragma unroll
  for(int ni = 0; ni < 4; ++ni){
    const float bvv = bias[n0 + wc + ni*16 + c16];
    const int gr = ni*2 + (c16 >> 3);
    const int within = (c16 & 7) * 2;
    #pragma unroll
    for(int mi = 0; mi < 4; ++mi)
      #pragma unroll
      for(int e = 0; e < 4; ++e){
        const int row = mi*16 + g*4 + e;
        *(u16*)(st + row*128 + ((gr ^ (row & 7)) << 4) + within)
            = f2b(acc[mi][ni][e] + bvv);
      }
  }
  asm volatile("s_waitcnt lgkmcnt(0)" ::: "memory");
  const int r8 = ln >> 3, jl = ln & 7;
  #pragma unroll
  for(int ii = 0; ii < 8; ++ii){
    const int row = ii*8 + r8;
    u16* dst = Cout + (size_t)(m0 + wr + row) * 1024 + n0 + wc + jl*8;
    *(u32x4*)dst = *(const u32x4*)(st + row*128 + ((jl ^ (row & 7)) << 4));
  }
}

// QK^T swapped-operand macro (r8-verified layout)
#define QKT(KB, Q00, Q01, Q10, Q11, S) do{                                             \
  _Pragma("unroll")                                                                    \
  for(int ch_ = 0; ch_ < 4; ++ch_){                                                    \
    const int r_ = ch_ * 16 + c;                                                       \
    bf16x8 ka0_ = *(const bf16x8*)((KB) + r_ * 64 + ((g       ^ (c & 7)) << 3));       \
    bf16x8 ka1_ = *(const bf16x8*)((KB) + r_ * 64 + (((4 + g) ^ (c & 7)) << 3));       \
    S[0][ch_] = __builtin_amdgcn_mfma_f32_16x16x32_bf16(ka0_, Q00, S[0][ch_], 0,0,0);  \
    S[0][ch_] = __builtin_amdgcn_mfma_f32_16x16x32_bf16(ka1_, Q01, S[0][ch_], 0,0,0);  \
    S[1][ch_] = __builtin_amdgcn_mfma_f32_16x16x32_bf16(ka0_, Q10, S[1][ch_], 0,0,0);  \
    S[1][ch_] = __builtin_amdgcn_mfma_f32_16x16x32_bf16(ka1_, Q11, S[1][ch_], 0,0,0);  \
  }                                                                                    \
}while(0)

// ---------------- fused attention v9: 2 q-tiles/block, p1(B) hidden under p2(A) -----
// grid (bh=64, bx=8) — bh fastest => same-bh blocks land on one XCD (K/V L2-local).
// Block owns q rows [bx*256, bx*256+256): tile A = first 128, tile B = second 128.
// Phases: p1(A) [r10 2-tile-unroll ring]; main loop = p2(A) with p1(B)'s QK^T+exp2
// inlined (reuses A's staged K tiles: zero extra staging/sync); tail = p2(B).
__global__ __launch_bounds__(256)
void attn9(const u16* __restrict__ Qb, const u16* __restrict__ Kb,
           const u16* __restrict__ Vt, float* __restrict__ attn_out,
           u16* __restrict__ AO)
{
  __shared__ __align__(16) u16 shm[32768];        // 64 KB (r10 layout)
  const int tid = threadIdx.x, w = tid >> 6, ln = tid & 63, g = ln >> 4, c = ln & 15;
  const int bh = blockIdx.x;
  const int q0A = blockIdx.y * 256 + w * 32;
  const int q0B = q0A + 128;

  const u16* QpA = Qb + ((size_t)bh * SS + q0A) * 64;
  const u16* QpB = Qb + ((size_t)bh * SS + q0B) * 64;
  const u16* Kp  = Kb + (size_t)bh * SS * 64;
  const u16* Vp  = Vt + (size_t)bh * 64 * SS;

  const bf16x8 qA00 = *(const bf16x8*)(QpA + c * 64 + g * 8);
  const bf16x8 qA01 = *(const bf16x8*)(QpA + c * 64 + 32 + g * 8);
  const bf16x8 qA10 = *(const bf16x8*)(QpA + (16 + c) * 64 + g * 8);
  const bf16x8 qA11 = *(const bf16x8*)(QpA + (16 + c) * 64 + 32 + g * 8);
  const bf16x8 qB00 = *(const bf16x8*)(QpB + c * 64 + g * 8);
  const bf16x8 qB01 = *(const bf16x8*)(QpB + c * 64 + 32 + g * 8);
  const bf16x8 qB10 = *(const bf16x8*)(QpB + (16 + c) * 64 + g * 8);
  const bf16x8 qB11 = *(const bf16x8*)(QpB + (16 + c) * 64 + 32 + g * 8);

  auto stageK = [&](int slot, int t){            // 2 vm ops / wave
    const u16* src = Kp + (size_t)t * 64 * 64;
    #pragma unroll
    for(int j = 0; j < 2; ++j){
      int idx = j * 256 + tid;
      int r = idx >> 3, s5 = idx & 7;
      gload16(src + r * 64 + (((s5 ^ (r & 7))) << 3), shm + slot * 4096 + (idx << 3));
    }
  };
  auto stageV = [&](int slot, int t){            // 2 vm ops / wave
    #pragma unroll
    for(int j = 0; j < 2; ++j){
      int idx = j * 256 + tid;
      int r = idx >> 3, s5 = idx & 7;
      gload16(Vp + (size_t)r * SS + t * 64 + (((s5 ^ (r & 7))) << 3),
              shm + 12288 + slot * 4096 + (idx << 3));
    }
  };

  u16* pw0 = shm + 24576 + w * 2048;
  u16* pw1 = pw0 + 1024;

  // pass-2 tile body (shared by main loop & tail) -------------------------------
  auto p2_tile = [&](int t, const u16* kb_, const u16* vb_,
                     const bf16x8& Q00, const bf16x8& Q01, const bf16x8& Q10, const bf16x8& Q11,
                     float rl0, float rl1, f32x4 (&acc)[2][4], float* aout, bool withB,
                     float& lB0, float& lB1){
    const int kv0 = t * 64;
    f32x4 s[2][4] = {};
    __builtin_amdgcn_s_setprio(1);
    QKT(kb_, Q00, Q01, Q10, Q11, s);
    __builtin_amdgcn_s_setprio(0);

    if(withB){   // p1(B): QK^T on the SAME staged K tile + exp2 accumulate (free staging)
      f32x4 sb[2][4] = {};
      __builtin_amdgcn_s_setprio(1);
      QKT(kb_, qB00, qB01, qB10, qB11, sb);
      __builtin_amdgcn_s_setprio(0);
      #pragma unroll
      for(int ch = 0; ch < 4; ++ch)
        #pragma unroll
        for(int e = 0; e < 4; ++e){
          lB0 += __builtin_amdgcn_exp2f(sb[0][ch][e]);
          lB1 += __builtin_amdgcn_exp2f(sb[1][ch][e]);
        }
    }

    #pragma unroll
    for(int qb = 0; qb < 2; ++qb){
      const float rl = qb ? rl1 : rl0;
      u16* pw = qb ? pw1 : pw0;
      #pragma unroll
      for(int ch = 0; ch < 4; ++ch){
        float p0 = __builtin_amdgcn_exp2f(s[qb][ch][0]) * rl;
        float p1 = __builtin_amdgcn_exp2f(s[qb][ch][1]) * rl;
        float p2 = __builtin_amdgcn_exp2f(s[qb][ch][2]) * rl;
        float p3 = __builtin_amdgcn_exp2f(s[qb][ch][3]) * rl;
        u32x2 pk2 = { cvtpk(p0, p1), cvtpk(p2, p3) };
        *(u32x2*)((char*)pw + c * 128 + (((ch * 2 + (g >> 1)) ^ (c & 7)) << 4) + ((g & 1) << 3)) = pk2;
      }
    }
    asm volatile("s_waitcnt lgkmcnt(0)" ::: "memory");
    __builtin_amdgcn_sched_barrier(0);

    __builtin_amdgcn_s_setprio(1);
    #pragma unroll
    for(int kc = 0; kc < 2; ++kc){
      bf16x8 ap0 = *(const bf16x8*)((const char*)pw0 + c * 128 + (((kc * 4 + g) ^ (c & 7)) << 4));
      bf16x8 ap1 = *(const bf16x8*)((const char*)pw1 + c * 128 + (((kc * 4 + g) ^ (c & 7)) << 4));
      #pragma unroll
      for(int ni = 0; ni < 4; ++ni){
        bf16x8 bv = *(const bf16x8*)(vb_ + (ni * 16 + c) * 64 + (((kc * 4 + g) ^ (c & 7)) << 3));
        acc[0][ni] = __builtin_amdgcn_mfma_f32_16x16x32_bf16(ap0, bv, acc[0][ni], 0, 0, 0);
        acc[1][ni] = __builtin_amdgcn_mfma_f32_16x16x32_bf16(ap1, bv, acc[1][ni], 0, 0, 0);
      }
    }
    __builtin_amdgcn_s_setprio(0);

    // FULL-LINE attn stores (8 rows x 128B per instruction) — r8-verified
    {
      const int r8 = ln >> 3;
      const int jl = ln & 7;
      #pragma unroll
      for(int qb = 0; qb < 2; ++qb){
        const u16* pw = qb ? pw1 : pw0;
        #pragma unroll
        for(int rh = 0; rh < 2; ++rh){
          const int r = rh * 8 + r8;
          #pragma unroll
          for(int chf = 0; chf < 2; ++chf){
            const int jg = chf * 8 + jl;
            const int ch2 = jg >> 2, g2 = jg & 3;
            const int slot = ch2 * 2 + (g2 >> 1);
            u32x2 pk = *(const u32x2*)((const char*)pw + r * 128 +
                         (((slot ^ (r & 7))) << 4) + ((g2 & 1) << 3));
            f32x4 o;
            o[0] = b2f((u16)(pk.x & 0xFFFFu)); o[1] = b2f((u16)(pk.x >> 16));
            o[2] = b2f((u16)(pk.y & 0xFFFFu)); o[3] = b2f((u16)(pk.y >> 16));
            *(f32x4*)(aout + (size_t)(qb * 16 + r) * SS + kv0 + jg * 4) = o;
          }
        }
      }
    }

    if(t == 0)       asm volatile("s_waitcnt vmcnt(12)" ::: "memory");
    else if(t < 30)  asm volatile("s_waitcnt vmcnt(20)" ::: "memory");
    else if(t == 30) asm volatile("s_waitcnt vmcnt(16)" ::: "memory");
    __builtin_amdgcn_s_barrier();
  };

  auto ao_epilogue = [&](f32x4 (&acc)[2][4], int q0){
    u16* aos = pw0;   // [32][64] u16 spans pw0+pw1
    #pragma unroll
    for(int qb = 0; qb < 2; ++qb)
      #pragma unroll
      for(int ni = 0; ni < 4; ++ni)
        #pragma unroll
        for(int e = 0; e < 4; ++e)
          aos[(qb * 16 + 4 * g + e) * 64 + ni * 16 + c] = f2b(acc[qb][ni][e]);
    asm volatile("s_waitcnt lgkmcnt(0)" ::: "memory");
    __builtin_amdgcn_sched_barrier(0);
    const int bb = bh >> 4, h = bh & 15;
    #pragma unroll
    for(int p2 = 0; p2 < 4; ++p2){
      int idx = p2 * 64 + ln;
      int row = idx >> 3, col16 = (idx & 7) * 8;
      u16* dst = AO + ((size_t)bb * SS + q0 + row) * 1024 + h * 64 + col16;
      *(u32x4*)dst = *(const u32x4*)(aos + row * 64 + col16);
    }
  };

  // ================= p1(A): denominators, 2 tiles per barrier (r10 verbatim) ======
  float l0 = 0.f, l1 = 0.f;
  auto comp1 = [&](const u16* kb_){
    f32x4 s[2][4] = {};
    QKT(kb_, qA00, qA01, qA10, qA11, s);
    #pragma unroll
    for(int ch = 0; ch < 4; ++ch)
      #pragma unroll
      for(int e = 0; e < 4; ++e){
        l0 += __builtin_amdgcn_exp2f(s[0][ch][e]);
        l1 += __builtin_amdgcn_exp2f(s[1][ch][e]);
      }
  };

  stageK(0, 0); stageK(1, 1);
  asm volatile("s_waitcnt vmcnt(2)" ::: "memory");
  __builtin_amdgcn_s_barrier();
  for(int t = 0; t < 32; t += 2){
    if(t < 30){ stageK((t + 2) & 3, t + 2); stageK((t + 3) & 3, t + 3); }
    __builtin_amdgcn_sched_barrier(0);
    comp1(shm + (t & 3) * 4096);
    if(t < 30) asm volatile("s_waitcnt vmcnt(4)" ::: "memory");
    else       asm volatile("s_waitcnt vmcnt(0)" ::: "memory");
    __builtin_amdgcn_sched_barrier(0);
    comp1(shm + ((t + 1) & 3) * 4096);
    if(t < 30) asm volatile("s_waitcnt vmcnt(2)" ::: "memory");
    __builtin_amdgcn_s_barrier();
  }
  l0 += __shfl_xor(l0, 16, 64); l0 += __shfl_xor(l0, 32, 64);
  l1 += __shfl_xor(l1, 16, 64); l1 += __shfl_xor(l1, 32, 64);
  const float rlA0 = 1.f / l0, rlA1 = 1.f / l1;

  // ================= main loop: p2(A) with p1(B) hidden under it ==================
  f32x4 accA[2][4] = {};
  float lB0 = 0.f, lB1 = 0.f;
  float* aoutA = attn_out + ((size_t)bh * SS + q0A) * SS;

  stageK(0, 0); stageV(0, 0); stageK(1, 1); stageV(1, 1);
  asm volatile("s_waitcnt vmcnt(4)" ::: "memory");
  __builtin_amdgcn_s_barrier();
  for(int t = 0; t < 32; ++t){
    if(t < 30){ stageK((t + 2) % 3, t + 2); stageV((t + 2) % 3, t + 2); }
    __builtin_amdgcn_sched_barrier(0);
    p2_tile(t, shm + (t % 3) * 4096, shm + 12288 + (t % 3) * 4096,
            qA00, qA01, qA10, qA11, rlA0, rlA1, accA, aoutA, true, lB0, lB1);
  }
  ao_epilogue(accA, q0A);

  lB0 += __shfl_xor(lB0, 16, 64); lB0 += __shfl_xor(lB0, 32, 64);
  lB1 += __shfl_xor(lB1, 16, 64); lB1 += __shfl_xor(lB1, 32, 64);
  const float rlB0 = 1.f / lB0, rlB1 = 1.f / lB1;

  // ================= tail: p2(B) ==================================================
  f32x4 accB[2][4] = {};
  float dum0, dum1;
  float* aoutB = attn_out + ((size_t)bh * SS + q0B) * SS;

  stageK(0, 0); stageV(0, 0); stageK(1, 1); stageV(1, 1);
  asm volatile("s_waitcnt vmcnt(4)" ::: "memory");
  __builtin_amdgcn_s_barrier();
  for(int t = 0; t < 32; ++t){
    if(t < 30){ stageK((t + 2) % 3, t + 2); stageV((t + 2) % 3, t + 2); }
    __builtin_amdgcn_sched_barrier(0);
    p2_tile(t, shm + (t % 3) * 4096, shm + 12288 + (t % 3) * 4096,
            qB00, qB01, qB10, qB11, rlB0, rlB1, accB, aoutB, false, dum0, dum1);
  }
  ao_epilogue(accB, q0B);
}

// ---------------- residual + LayerNorm (bf16 tmp input) -----------------------------
__global__ __launch_bounds__(256)
void ln_kernel(const u16* __restrict__ tmpb, const float* __restrict__ qin,
               const float* __restrict__ gamma, const float* __restrict__ beta,
               float* __restrict__ out)
{
  __shared__ float rs[4], rs2[4];
  const int row = blockIdx.x, tid = threadIdx.x;
  const int w = tid >> 6, ln = tid & 63;
  const uint2 tv = *(const uint2*)(tmpb + (size_t)row * 1024 + tid * 4);
  const float4 q4 = *(const float4*)(qin + (size_t)row * 1024 + tid * 4);
  const float xs0 = b2f((u16)(tv.x & 0xFFFFu)) + q4.x;
  const float xs1 = b2f((u16)(tv.x >> 16))     + q4.y;
  const float xs2 = b2f((u16)(tv.y & 0xFFFFu)) + q4.z;
  const float xs3 = b2f((u16)(tv.y >> 16))     + q4.w;
  float s  = xs0 + xs1 + xs2 + xs3;
  float s2 = xs0*xs0 + xs1*xs1 + xs2*xs2 + xs3*xs3;
  #pragma unroll
  for(int m = 1; m < 64; m <<= 1){
    s  += __shfl_xor(s,  m, 64);
    s2 += __shfl_xor(s2, m, 64);
  }
  if(ln == 0){ rs[w] = s; rs2[w] = s2; }
  __syncthreads();
  s  = rs[0]  + rs[1]  + rs[2]  + rs[3];
  s2 = rs2[0] + rs2[1] + rs2[2] + rs2[3];
  const float mu   = s * (1.f / 1024.f);
  const float var  = s2 * (1.f / 1024.f) - mu * mu;
  const float rstd = rsqrtf(var + 1e-5f);
  const float4 g4 = *(const float4*)(gamma + tid * 4);
  const float4 b4 = *(const float4*)(beta + tid * 4);
  float4 o;
  o.x = (xs0 - mu) * rstd * g4.x + b4.x;
  o.y = (xs1 - mu) * rstd * g4.y + b4.y;
  o.z = (xs2 - mu) * rstd * g4.z + b4.z;
  o.w = (xs3 - mu) * rstd * g4.w + b4.w;
  *(float4*)(out + (size_t)row * 1024 + tid * 4) = o;
}

// ------------------------------------------------------------------------------------
extern "C" void kernel_launch(void* const* d_in, const int* in_sizes, int n_in,
                              void* d_out, int out_size, void* d_ws, size_t ws_size,
                              hipStream_t stream)
{
  (void)in_sizes; (void)n_in; (void)out_size; (void)ws_size;
  const float* q     = (const float*)d_in[0];
  const float* k     = (const float*)d_in[1];
  const float* v     = (const float*)d_in[2];
  const float* Wq    = (const float*)d_in[3];
  const float* bq    = (const float*)d_in[4];
  const float* Wk    = (const float*)d_in[5];
  const float* bk    = (const float*)d_in[6];
  const float* Wv    = (const float*)d_in[7];
  const float* bv    = (const float*)d_in[8];
  const float* Wo    = (const float*)d_in[9];
  const float* bo    = (const float*)d_in[10];
  const float* gamma = (const float*)d_in[11];
  const float* beta  = (const float*)d_in[12];

  char* p = (char*)d_ws;
  auto alloc = [&](size_t bytes) -> void* {
    void* r = (void*)p; p += (bytes + 255) & ~(size_t)255; return r;
  };
  const size_t NTOK = (size_t)BB * SS;           // 8192
  u16* WtQ  = (u16*)alloc((size_t)DD * DD * 2);
  u16* WtK  = (u16*)alloc((size_t)DD * DD * 2);
  u16* WtV  = (u16*)alloc((size_t)DD * DD * 2);
  u16* WtO  = (u16*)alloc((size_t)DD * DD * 2);
  u16* Qb   = (u16*)alloc(NTOK * DD * 2);
  u16* Kb   = (u16*)alloc(NTOK * DD * 2);
  u16* Vtb  = (u16*)alloc(NTOK * DD * 2);
  u16* AO   = (u16*)alloc(NTOK * DD * 2);
  u16* qbf  = (u16*)alloc(NTOK * DD * 2);
  u16* kbf  = (u16*)alloc(NTOK * DD * 2);
  u16* vbf  = (u16*)alloc(NTOK * DD * 2);
  u16* tmpb = (u16*)alloc(NTOK * DD * 2);

  float* out0 = (float*)d_out;
  float* attn = out0 + NTOK * DD;                // [B,H,S,S]

  const int NPACK = (int)(NTOK * DD / 8);
  cvt_bf16_3<<<dim3(1024, 3), 256, 0, stream>>>(q, k, v, qbf, kbf, vbf, NPACK);

  transpose_cvt4<<<dim3(16, 16, 4), 256, 0, stream>>>(
      Wq, Wk, Wv, Wo, WtQ, WtK, WtV, WtO);

  gemm_qkv<<<dim3(8, 64, 3), 256, 0, stream>>>(
      qbf, kbf, vbf, WtQ, WtK, WtV, bq, bk, bv, Qb, Kb, Vtb);

  attn9<<<dim3(64, 8), 256, 0, stream>>>(Qb, Kb, Vtb, attn, AO);

  gemm_o<<<dim3(8, 64), 256, 0, stream>>>(AO, WtO, bo, tmpb);
  ln_kernel<<<dim3(8192), 256, 0, stream>>>(tmpb, q, gamma, beta, out0);
}

// Round 12
// 461.111 us; speedup vs baseline: 1.1640x; 1.1640x over previous
//
#include <hip/hip_runtime.h>
#include <stdint.h>

typedef unsigned short u16;
typedef unsigned int   u32;
typedef __attribute__((ext_vector_type(8))) short bf16x8;
typedef __attribute__((ext_vector_type(4))) float f32x4;
typedef __attribute__((ext_vector_type(4))) u32   u32x4;
typedef __attribute__((ext_vector_type(2))) u32   u32x2;

// Problem constants
#define BB 4
#define SS 2048
#define DD 1024
#define HH 16
// DK = DV = 64
// fold 1/sqrt(DK) * log2(e) into Q so attn softmax uses exp2 directly
#define QSCALE 0.18033688011112042f

__device__ __forceinline__ u16 f2b(float f){
  u32 u = __builtin_bit_cast(u32, f);
  u32 r = (u + 0x7FFFu + ((u >> 16) & 1u)) >> 16;   // RNE bf16 (finite values only)
  return (u16)r;
}
__device__ __forceinline__ float b2f(u16 h){
  return __builtin_bit_cast(float, (u32)h << 16);
}
__device__ __forceinline__ u32 cvtpk(float lo, float hi){
  u32 r; asm("v_cvt_pk_bf16_f32 %0, %1, %2" : "=v"(r) : "v"(lo), "v"(hi)); return r;
}

// async global->LDS, 16B per lane; lds base must be wave-uniform + lane*16.
__device__ __forceinline__ void gload16(const u16* g, u16* l){
  __builtin_amdgcn_global_load_lds(
      (const __attribute__((address_space(1))) void*)(uintptr_t)g,
      (__attribute__((address_space(3))) void*)(uintptr_t)l,
      16, 0, 0);
}

// ---------------- f32 -> bf16 bulk convert, 3 tensors in one launch -----------------
__global__ __launch_bounds__(256)
void cvt_bf16_3(const float* __restrict__ q, const float* __restrict__ k,
                const float* __restrict__ v, u16* __restrict__ qo,
                u16* __restrict__ ko, u16* __restrict__ vo, int npack)
{
  const float* in = blockIdx.y == 0 ? q : (blockIdx.y == 1 ? k : v);
  u16* out        = blockIdx.y == 0 ? qo : (blockIdx.y == 1 ? ko : vo);
  for(int i = blockIdx.x * 256 + threadIdx.x; i < npack; i += gridDim.x * 256){
    const float4* p = (const float4*)in + 2 * (size_t)i;
    float4 a = p[0], b = p[1];
    u32x4 o;
    o.x = f2b(a.x) | ((u32)f2b(a.y) << 16);
    o.y = f2b(a.z) | ((u32)f2b(a.w) << 16);
    o.z = f2b(b.x) | ((u32)f2b(b.y) << 16);
    o.w = f2b(b.z) | ((u32)f2b(b.w) << 16);
    ((u32x4*)out)[i] = o;
  }
}

// ---------------- weight transpose + bf16 convert, 64x64 tiles, full-line stores ----
__global__ __launch_bounds__(256)
void transpose_cvt4(const float* __restrict__ W0, const float* __restrict__ W1,
                    const float* __restrict__ W2, const float* __restrict__ W3,
                    u16* __restrict__ T0, u16* __restrict__ T1,
                    u16* __restrict__ T2, u16* __restrict__ T3)
{
  const float* W = blockIdx.z == 0 ? W0 : (blockIdx.z == 1 ? W1 : (blockIdx.z == 2 ? W2 : W3));
  u16*        Wt = blockIdx.z == 0 ? T0 : (blockIdx.z == 1 ? T1 : (blockIdx.z == 2 ? T2 : T3));
  __shared__ float tile[64][65];
  const int tid = threadIdx.x;
  const int n0 = blockIdx.x * 64, k0 = blockIdx.y * 64;
  const int lr = tid >> 4, lc = tid & 15;
  #pragma unroll
  for(int i = 0; i < 4; ++i){
    float4 v = *(const float4*)(W + (size_t)(k0 + lr + 16*i) * DD + n0 + lc * 4);
    tile[lr + 16*i][lc*4 + 0] = v.x;
    tile[lr + 16*i][lc*4 + 1] = v.y;
    tile[lr + 16*i][lc*4 + 2] = v.z;
    tile[lr + 16*i][lc*4 + 3] = v.w;
  }
  __syncthreads();
  // Wt[n0+row][k0+seg*8 .. +7] = tile[seg*8+j][row]
  #pragma unroll
  for(int j = 0; j < 2; ++j){
    int idx = j * 256 + tid;
    int row = idx >> 3, seg = idx & 7;
    u32x4 o;
    o.x = f2b(tile[seg*8+0][row]) | ((u32)f2b(tile[seg*8+1][row]) << 16);
    o.y = f2b(tile[seg*8+2][row]) | ((u32)f2b(tile[seg*8+3][row]) << 16);
    o.z = f2b(tile[seg*8+4][row]) | ((u32)f2b(tile[seg*8+5][row]) << 16);
    o.w = f2b(tile[seg*8+6][row]) | ((u32)f2b(tile[seg*8+7][row]) << 16);
    *(u32x4*)(Wt + (size_t)(n0 + row) * DD + k0 + seg * 8) = o;
  }
}

// ---------------- merged QKV GEMM (blockIdx.z = mode), full-line LDS epilogue -------
__global__ __launch_bounds__(256)
void gemm_qkv(const u16* __restrict__ qA, const u16* __restrict__ kA, const u16* __restrict__ vA,
              const u16* __restrict__ BtQ, const u16* __restrict__ BtK, const u16* __restrict__ BtV,
              const float* __restrict__ bq, const float* __restrict__ bk, const float* __restrict__ bv,
              u16* __restrict__ Qo, u16* __restrict__ Ko, u16* __restrict__ Vo)
{
  const int mode = blockIdx.z;
  const u16* A   = mode == 0 ? qA  : (mode == 1 ? kA  : vA);
  const u16* Bt  = mode == 0 ? BtQ : (mode == 1 ? BtK : BtV);
  const float* bias = mode == 0 ? bq : (mode == 1 ? bk : bv);
  u16* Cout      = mode == 0 ? Qo  : (mode == 1 ? Ko  : Vo);

  __shared__ __align__(16) u16 smem[16384];       // 32KB: K-loop uses 16KB; epilogue 32KB
  u16* As = smem;
  u16* Bs = smem + 128*32;
  const int tid = threadIdx.x;
  const int w = tid >> 6, ln = tid & 63, g = ln >> 4, c16 = ln & 15;
  const int m0 = blockIdx.y * 128, n0 = blockIdx.x * 128;
  const int wr = (w >> 1) * 64, wc = (w & 1) * 64;

  f32x4 acc[4][4] = {};

  for(int kt = 0; kt < 1024; kt += 32){
    __syncthreads();
    {
      const int f0 = w * 2;
      #pragma unroll
      for(int j = 0; j < 2; ++j){
        int e = ((f0 + j) * 64 + ln) * 8;
        gload16(Bt + (size_t)(n0 + (e >> 5)) * 1024 + kt + (e & 31),
                Bs + (size_t)(f0 + j) * 512);
        gload16(A + (size_t)(m0 + (e >> 5)) * 1024 + kt + (e & 31),
                As + (size_t)(f0 + j) * 512);
      }
    }
    __syncthreads();
    bf16x8 a[4], b[4];
    #pragma unroll
    for(int mi = 0; mi < 4; ++mi)
      a[mi] = *(const bf16x8*)(As + (wr + mi*16 + c16) * 32 + g * 8);
    #pragma unroll
    for(int ni = 0; ni < 4; ++ni)
      b[ni] = *(const bf16x8*)(Bs + (wc + ni*16 + c16) * 32 + g * 8);
    #pragma unroll
    for(int mi = 0; mi < 4; ++mi)
      #pragma unroll
      for(int ni = 0; ni < 4; ++ni)
        acc[mi][ni] = __builtin_amdgcn_mfma_f32_16x16x32_bf16(a[mi], b[ni], acc[mi][ni], 0, 0, 0);
  }
  __syncthreads();    // all waves' last ds_reads done; smem reused as 4x8KB stage

  char* st = (char*)smem + w * 8192;   // per-wave [64 rows][128B], XOR-swizzled 16B slots
  const float sc = (mode == 0) ? QSCALE : 1.f;
  const int bb = m0 >> 11;
  const int h  = (n0 + wc) >> 6;
  const int sbase = (m0 + wr) & 2047;

  if(mode < 2){
    #pragma unroll
    for(int ni = 0; ni < 4; ++ni){
      const float bvv = bias[n0 + wc + ni*16 + c16];
      const int gr = ni*2 + (c16 >> 3);
      const int within = (c16 & 7) * 2;
      #pragma unroll
      for(int mi = 0; mi < 4; ++mi)
        #pragma unroll
        for(int e = 0; e < 4; ++e){
          const int row = mi*16 + g*4 + e;
          *(u16*)(st + row*128 + ((gr ^ (row & 7)) << 4) + within)
              = f2b((acc[mi][ni][e] + bvv) * sc);
        }
    }
    asm volatile("s_waitcnt lgkmcnt(0)" ::: "memory");
    const int r8 = ln >> 3, jl = ln & 7;
    #pragma unroll
    for(int ii = 0; ii < 8; ++ii){
      const int row = ii*8 + r8;
      u16* dst = Cout + (((size_t)(bb*HH + h) * SS) + sbase + row) * 64 + jl*8;
      *(u32x4*)dst = *(const u32x4*)(st + row*128 + ((jl ^ (row & 7)) << 4));
    }
  } else {
    #pragma unroll
    for(int ni = 0; ni < 4; ++ni){
      const float bvv = bias[n0 + wc + ni*16 + c16];
      const int row = ni*16 + c16;      // d-local
      #pragma unroll
      for(int mi = 0; mi < 4; ++mi)
        #pragma unroll
        for(int e = 0; e < 4; ++e){
          const int sl = mi*16 + g*4 + e;   // s-local
          const int gr = sl >> 3;
          *(u16*)(st + row*128 + ((gr ^ (row & 7)) << 4) + (sl & 7) * 2)
              = f2b(acc[mi][ni][e] + bvv);
        }
    }
    asm volatile("s_waitcnt lgkmcnt(0)" ::: "memory");
    const int r8 = ln >> 3, jl = ln & 7;
    #pragma unroll
    for(int ii = 0; ii < 8; ++ii){
      const int d = ii*8 + r8;
      u16* dst = Cout + ((size_t)(bb*HH + h) * 64 + (n0 + wc - ((n0+wc)>>6<<6)) + d) * SS + sbase + jl*8;
      *(u32x4*)dst = *(const u32x4*)(st + d*128 + ((jl ^ (d & 7)) << 4));
    }
  }
}

// ---------------- out-proj GEMM -> bf16 tmp, full-line LDS epilogue -----------------
__global__ __launch_bounds__(256)
void gemm_o(const u16* __restrict__ A, const u16* __restrict__ Bt,
            const float* __restrict__ bias, u16* __restrict__ Cout)
{
  __shared__ __align__(16) u16 smem[16384];
  u16* As = smem;
  u16* Bs = smem + 128*32;
  const int tid = threadIdx.x;
  const int w = tid >> 6, ln = tid & 63, g = ln >> 4, c16 = ln & 15;
  const int m0 = blockIdx.y * 128, n0 = blockIdx.x * 128;
  const int wr = (w >> 1) * 64, wc = (w & 1) * 64;

  f32x4 acc[4][4] = {};

  for(int kt = 0; kt < 1024; kt += 32){
    __syncthreads();
    {
      const int f0 = w * 2;
      #pragma unroll
      for(int j = 0; j < 2; ++j){
        int e = ((f0 + j) * 64 + ln) * 8;
        gload16(Bt + (size_t)(n0 + (e >> 5)) * 1024 + kt + (e & 31),
                Bs + (size_t)(f0 + j) * 512);
        gload16(A + (size_t)(m0 + (e >> 5)) * 1024 + kt + (e & 31),
                As + (size_t)(f0 + j) * 512);
      }
    }
    __syncthreads();
    bf16x8 a[4], b[4];
    #pragma unroll
    for(int mi = 0; mi < 4; ++mi)
      a[mi] = *(const bf16x8*)(As + (wr + mi*16 + c16) * 32 + g * 8);
    #pragma unroll
    for(int ni = 0; ni < 4; ++ni)
      b[ni] = *(const bf16x8*)(Bs + (wc + ni*16 + c16) * 32 + g * 8);
    #pragma unroll
    for(int mi = 0; mi < 4; ++mi)
      #pragma unroll
      for(int ni = 0; ni < 4; ++ni)
        acc[mi][ni] = __builtin_amdgcn_mfma_f32_16x16x32_bf16(a[mi], b[ni], acc[mi][ni], 0, 0, 0);
  }
  __syncthreads();

  char* st = (char*)smem + w * 8192;   // per-wave [64 rows][64 bf16 = 128B] swizzled
  #pragma unroll
  for(int ni = 0; ni < 4; ++ni){
    const float bvv = bias[n0 + wc + ni*16 + c16];
    const int gr = ni*2 + (c16 >> 3);
    const int within = (c16 & 7) * 2;
    #pragma unroll
    for(int mi = 0; mi < 4; ++mi)
      #pragma unroll
      for(int e = 0; e < 4; ++e){
        const int row = mi*16 + g*4 + e;
        *(u16*)(st + row*128 + ((gr ^ (row & 7)) << 4) + within)
            = f2b(acc[mi][ni][e] + bvv);
      }
  }
  asm volatile("s_waitcnt lgkmcnt(0)" ::: "memory");
  const int r8 = ln >> 3, jl = ln & 7;
  #pragma unroll
  for(int ii = 0; ii < 8; ++ii){
    const int row = ii*8 + r8;
    u16* dst = Cout + (size_t)(m0 + wr + row) * 1024 + n0 + wc + jl*8;
    *(u32x4*)dst = *(const u32x4*)(st + row*128 + ((jl ^ (row & 7)) << 4));
  }
}

// ---------------- fused attention v8: pass-1 2-tile unroll, else round-8 verbatim ---
__global__ __launch_bounds__(256)
void attn8(const u16* __restrict__ Qb, const u16* __restrict__ Kb,
           const u16* __restrict__ Vt, float* __restrict__ attn_out,
           u16* __restrict__ AO)
{
  __shared__ __align__(16) u16 shm[32768];        // 64 KB
  // pass 1: K ring = shm, 4 slots x 4096 u16
  // pass 2: Ks = shm (3 slots x 4096), Vs = shm+12288 (3 x 4096), pbuf = shm+24576
  const int tid = threadIdx.x, w = tid >> 6, ln = tid & 63, g = ln >> 4, c = ln & 15;
  const int bh = blockIdx.y;
  const int q0 = blockIdx.x * 128 + w * 32;

  const u16* Qp = Qb + ((size_t)bh * SS + q0) * 64;
  const u16* Kp = Kb + (size_t)bh * SS * 64;
  const u16* Vp = Vt + (size_t)bh * 64 * SS;

  const bf16x8 bq00 = *(const bf16x8*)(Qp + c * 64 + g * 8);
  const bf16x8 bq01 = *(const bf16x8*)(Qp + c * 64 + 32 + g * 8);
  const bf16x8 bq10 = *(const bf16x8*)(Qp + (16 + c) * 64 + g * 8);
  const bf16x8 bq11 = *(const bf16x8*)(Qp + (16 + c) * 64 + 32 + g * 8);

  auto stageK = [&](int slot, int t){            // 2 vm ops / wave, slot 0..3
    const u16* src = Kp + (size_t)t * 64 * 64;
    #pragma unroll
    for(int j = 0; j < 2; ++j){
      int idx = j * 256 + tid;
      int r = idx >> 3, s5 = idx & 7;
      gload16(src + r * 64 + (((s5 ^ (r & 7))) << 3), shm + slot * 4096 + (idx << 3));
    }
  };
  auto stageV = [&](int slot, int t){            // 2 vm ops / wave, slot 0..2
    #pragma unroll
    for(int j = 0; j < 2; ++j){
      int idx = j * 256 + tid;
      int r = idx >> 3, s5 = idx & 7;
      gload16(Vp + (size_t)r * SS + t * 64 + (((s5 ^ (r & 7))) << 3),
              shm + 12288 + slot * 4096 + (idx << 3));
    }
  };

  // ================= pass 1: denominators, 2 tiles per barrier =================
  float l0 = 0.f, l1 = 0.f;
  auto comp1 = [&](const u16* kb_){
    f32x4 s[2][4] = {};
    #pragma unroll
    for(int ch = 0; ch < 4; ++ch){
      const int r = ch * 16 + c;
      bf16x8 ka0 = *(const bf16x8*)(kb_ + r * 64 + ((g       ^ (c & 7)) << 3));
      bf16x8 ka1 = *(const bf16x8*)(kb_ + r * 64 + (((4 + g) ^ (c & 7)) << 3));
      s[0][ch] = __builtin_amdgcn_mfma_f32_16x16x32_bf16(ka0, bq00, s[0][ch], 0, 0, 0);
      s[0][ch] = __builtin_amdgcn_mfma_f32_16x16x32_bf16(ka1, bq01, s[0][ch], 0, 0, 0);
      s[1][ch] = __builtin_amdgcn_mfma_f32_16x16x32_bf16(ka0, bq10, s[1][ch], 0, 0, 0);
      s[1][ch] = __builtin_amdgcn_mfma_f32_16x16x32_bf16(ka1, bq11, s[1][ch], 0, 0, 0);
    }
    #pragma unroll
    for(int ch = 0; ch < 4; ++ch)
      #pragma unroll
      for(int e = 0; e < 4; ++e){
        l0 += __builtin_amdgcn_exp2f(s[0][ch][e]);
        l1 += __builtin_amdgcn_exp2f(s[1][ch][e]);
      }
  };

  stageK(0, 0); stageK(1, 1);
  asm volatile("s_waitcnt vmcnt(2)" ::: "memory");   // tile0 resident; tile1 in flight
  __builtin_amdgcn_s_barrier();
  for(int t = 0; t < 32; t += 2){
    if(t < 30){ stageK((t + 2) & 3, t + 2); stageK((t + 3) & 3, t + 3); }
    __builtin_amdgcn_sched_barrier(0);
    comp1(shm + (t & 3) * 4096);                     // tile t (resident at entry)
    if(t < 30) asm volatile("s_waitcnt vmcnt(4)" ::: "memory");  // tile t+1 resident
    else       asm volatile("s_waitcnt vmcnt(0)" ::: "memory");
    __builtin_amdgcn_sched_barrier(0);
    comp1(shm + ((t + 1) & 3) * 4096);               // tile t+1
    if(t < 30) asm volatile("s_waitcnt vmcnt(2)" ::: "memory");  // tile t+2 resident
    __builtin_amdgcn_s_barrier();
  }
  l0 += __shfl_xor(l0, 16, 64); l0 += __shfl_xor(l0, 32, 64);
  l1 += __shfl_xor(l1, 16, 64); l1 += __shfl_xor(l1, 32, 64);
  const float rl0 = 1.f / l0, rl1 = 1.f / l1;

  // ================= pass 2: recompute + write attn + PV (round-8 verbatim) ========
  f32x4 acc[2][4] = {};
  float* aout = attn_out + ((size_t)bh * SS + q0) * SS;
  u16* pw0 = shm + 24576 + w * 2048;
  u16* pw1 = pw0 + 1024;

  stageK(0, 0); stageV(0, 0); stageK(1, 1); stageV(1, 1);
  asm volatile("s_waitcnt vmcnt(4)" ::: "memory");
  __builtin_amdgcn_s_barrier();

  for(int t = 0; t < 32; ++t){
    if(t < 30){ stageK((t + 2) % 3, t + 2); stageV((t + 2) % 3, t + 2); }
    __builtin_amdgcn_sched_barrier(0);
    const int kv0 = t * 64;
    const u16* kb_ = shm + (t % 3) * 4096;
    const u16* vb_ = shm + 12288 + (t % 3) * 4096;

    f32x4 s[2][4] = {};
    __builtin_amdgcn_s_setprio(1);
    #pragma unroll
    for(int ch = 0; ch < 4; ++ch){
      const int r = ch * 16 + c;
      bf16x8 ka0 = *(const bf16x8*)(kb_ + r * 64 + ((g       ^ (c & 7)) << 3));
      bf16x8 ka1 = *(const bf16x8*)(kb_ + r * 64 + (((4 + g) ^ (c & 7)) << 3));
      s[0][ch] = __builtin_amdgcn_mfma_f32_16x16x32_bf16(ka0, bq00, s[0][ch], 0, 0, 0);
      s[0][ch] = __builtin_amdgcn_mfma_f32_16x16x32_bf16(ka1, bq01, s[0][ch], 0, 0, 0);
      s[1][ch] = __builtin_amdgcn_mfma_f32_16x16x32_bf16(ka0, bq10, s[1][ch], 0, 0, 0);
      s[1][ch] = __builtin_amdgcn_mfma_f32_16x16x32_bf16(ka1, bq11, s[1][ch], 0, 0, 0);
    }
    __builtin_amdgcn_s_setprio(0);

    #pragma unroll
    for(int qb = 0; qb < 2; ++qb){
      const float rl = qb ? rl1 : rl0;
      u16* pw = qb ? pw1 : pw0;
      #pragma unroll
      for(int ch = 0; ch < 4; ++ch){
        float p0 = __builtin_amdgcn_exp2f(s[qb][ch][0]) * rl;
        float p1 = __builtin_amdgcn_exp2f(s[qb][ch][1]) * rl;
        float p2 = __builtin_amdgcn_exp2f(s[qb][ch][2]) * rl;
        float p3 = __builtin_amdgcn_exp2f(s[qb][ch][3]) * rl;
        u32x2 pk2 = { cvtpk(p0, p1), cvtpk(p2, p3) };
        *(u32x2*)((char*)pw + c * 128 + (((ch * 2 + (g >> 1)) ^ (c & 7)) << 4) + ((g & 1) << 3)) = pk2;
      }
    }
    asm volatile("s_waitcnt lgkmcnt(0)" ::: "memory");
    __builtin_amdgcn_sched_barrier(0);

    __builtin_amdgcn_s_setprio(1);
    #pragma unroll
    for(int kc = 0; kc < 2; ++kc){
      bf16x8 ap0 = *(const bf16x8*)((const char*)pw0 + c * 128 + (((kc * 4 + g) ^ (c & 7)) << 4));
      bf16x8 ap1 = *(const bf16x8*)((const char*)pw1 + c * 128 + (((kc * 4 + g) ^ (c & 7)) << 4));
      #pragma unroll
      for(int ni = 0; ni < 4; ++ni){
        bf16x8 bv = *(const bf16x8*)(vb_ + (ni * 16 + c) * 64 + (((kc * 4 + g) ^ (c & 7)) << 3));
        acc[0][ni] = __builtin_amdgcn_mfma_f32_16x16x32_bf16(ap0, bv, acc[0][ni], 0, 0, 0);
        acc[1][ni] = __builtin_amdgcn_mfma_f32_16x16x32_bf16(ap1, bv, acc[1][ni], 0, 0, 0);
      }
    }
    __builtin_amdgcn_s_setprio(0);

    // ---- attn write phase: FULL-LINE stores from pbuf (8 rows x 128B per instr)
    {
      const int r8 = ln >> 3;
      const int jl = ln & 7;
      #pragma unroll
      for(int qb = 0; qb < 2; ++qb){
        const u16* pw = qb ? pw1 : pw0;
        #pragma unroll
        for(int rh = 0; rh < 2; ++rh){
          const int r = rh * 8 + r8;
          #pragma unroll
          for(int chf = 0; chf < 2; ++chf){
            const int jg = chf * 8 + jl;
            const int ch2 = jg >> 2, g2 = jg & 3;
            const int slot = ch2 * 2 + (g2 >> 1);
            u32x2 pk = *(const u32x2*)((const char*)pw + r * 128 +
                         (((slot ^ (r & 7))) << 4) + ((g2 & 1) << 3));
            f32x4 o;
            o[0] = b2f((u16)(pk.x & 0xFFFFu)); o[1] = b2f((u16)(pk.x >> 16));
            o[2] = b2f((u16)(pk.y & 0xFFFFu)); o[3] = b2f((u16)(pk.y >> 16));
            *(f32x4*)(aout + (size_t)(qb * 16 + r) * SS + kv0 + jg * 4) = o;
          }
        }
      }
    }

    if(t == 0)       asm volatile("s_waitcnt vmcnt(12)" ::: "memory");
    else if(t < 30)  asm volatile("s_waitcnt vmcnt(20)" ::: "memory");
    else if(t == 30) asm volatile("s_waitcnt vmcnt(16)" ::: "memory");
    __builtin_amdgcn_s_barrier();
  }

  // ---- AO epilogue
  u16* aos = pw0;   // [32][64] u16 = 2048, spans pw0+pw1
  #pragma unroll
  for(int qb = 0; qb < 2; ++qb)
    #pragma unroll
    for(int ni = 0; ni < 4; ++ni)
      #pragma unroll
      for(int e = 0; e < 4; ++e)
        aos[(qb * 16 + 4 * g + e) * 64 + ni * 16 + c] = f2b(acc[qb][ni][e]);
  asm volatile("s_waitcnt lgkmcnt(0)" ::: "memory");
  __builtin_amdgcn_sched_barrier(0);
  {
    const int bb = bh >> 4, h = bh & 15;
    #pragma unroll
    for(int p2 = 0; p2 < 4; ++p2){
      int idx = p2 * 64 + ln;
      int row = idx >> 3, col16 = (idx & 7) * 8;
      u16* dst = AO + ((size_t)bb * SS + q0 + row) * 1024 + h * 64 + col16;
      *(u32x4*)dst = *(const u32x4*)(aos + row * 64 + col16);
    }
  }
}

// ---------------- residual + LayerNorm (bf16 tmp input) -----------------------------
__global__ __launch_bounds__(256)
void ln_kernel(const u16* __restrict__ tmpb, const float* __restrict__ qin,
               const float* __restrict__ gamma, const float* __restrict__ beta,
               float* __restrict__ out)
{
  __shared__ float rs[4], rs2[4];
  const int row = blockIdx.x, tid = threadIdx.x;
  const int w = tid >> 6, ln = tid & 63;
  const uint2 tv = *(const uint2*)(tmpb + (size_t)row * 1024 + tid * 4);
  const float4 q4 = *(const float4*)(qin + (size_t)row * 1024 + tid * 4);
  const float xs0 = b2f((u16)(tv.x & 0xFFFFu)) + q4.x;
  const float xs1 = b2f((u16)(tv.x >> 16))     + q4.y;
  const float xs2 = b2f((u16)(tv.y & 0xFFFFu)) + q4.z;
  const float xs3 = b2f((u16)(tv.y >> 16))     + q4.w;
  float s  = xs0 + xs1 + xs2 + xs3;
  float s2 = xs0*xs0 + xs1*xs1 + xs2*xs2 + xs3*xs3;
  #pragma unroll
  for(int m = 1; m < 64; m <<= 1){
    s  += __shfl_xor(s,  m, 64);
    s2 += __shfl_xor(s2, m, 64);
  }
  if(ln == 0){ rs[w] = s; rs2[w] = s2; }
  __syncthreads();
  s  = rs[0]  + rs[1]  + rs[2]  + rs[3];
  s2 = rs2[0] + rs2[1] + rs2[2] + rs2[3];
  const float mu   = s * (1.f / 1024.f);
  const float var  = s2 * (1.f / 1024.f) - mu * mu;
  const float rstd = rsqrtf(var + 1e-5f);
  const float4 g4 = *(const float4*)(gamma + tid * 4);
  const float4 b4 = *(const float4*)(beta + tid * 4);
  float4 o;
  o.x = (xs0 - mu) * rstd * g4.x + b4.x;
  o.y = (xs1 - mu) * rstd * g4.y + b4.y;
  o.z = (xs2 - mu) * rstd * g4.z + b4.z;
  o.w = (xs3 - mu) * rstd * g4.w + b4.w;
  *(float4*)(out + (size_t)row * 1024 + tid * 4) = o;
}

// ------------------------------------------------------------------------------------
extern "C" void kernel_launch(void* const* d_in, const int* in_sizes, int n_in,
                              void* d_out, int out_size, void* d_ws, size_t ws_size,
                              hipStream_t stream)
{
  (void)in_sizes; (void)n_in; (void)out_size; (void)ws_size;
  const float* q     = (const float*)d_in[0];
  const float* k     = (const float*)d_in[1];
  const float* v     = (const float*)d_in[2];
  const float* Wq    = (const float*)d_in[3];
  const float* bq    = (const float*)d_in[4];
  const float* Wk    = (const float*)d_in[5];
  const float* bk    = (const float*)d_in[6];
  const float* Wv    = (const float*)d_in[7];
  const float* bv    = (const float*)d_in[8];
  const float* Wo    = (const float*)d_in[9];
  const float* bo    = (const float*)d_in[10];
  const float* gamma = (const float*)d_in[11];
  const float* beta  = (const float*)d_in[12];

  char* p = (char*)d_ws;
  auto alloc = [&](size_t bytes) -> void* {
    void* r = (void*)p; p += (bytes + 255) & ~(size_t)255; return r;
  };
  const size_t NTOK = (size_t)BB * SS;           // 8192
  u16* WtQ  = (u16*)alloc((size_t)DD * DD * 2);
  u16* WtK  = (u16*)alloc((size_t)DD * DD * 2);
  u16* WtV  = (u16*)alloc((size_t)DD * DD * 2);
  u16* WtO  = (u16*)alloc((size_t)DD * DD * 2);
  u16* Qb   = (u16*)alloc(NTOK * DD * 2);
  u16* Kb   = (u16*)alloc(NTOK * DD * 2);
  u16* Vtb  = (u16*)alloc(NTOK * DD * 2);
  u16* AO   = (u16*)alloc(NTOK * DD * 2);
  u16* qbf  = (u16*)alloc(NTOK * DD * 2);
  u16* kbf  = (u16*)alloc(NTOK * DD * 2);
  u16* vbf  = (u16*)alloc(NTOK * DD * 2);
  u16* tmpb = (u16*)alloc(NTOK * DD * 2);

  float* out0 = (float*)d_out;
  float* attn = out0 + NTOK * DD;                // [B,H,S,S]

  const int NPACK = (int)(NTOK * DD / 8);        // 1,048,576 packs of 8
  cvt_bf16_3<<<dim3(1024, 3), 256, 0, stream>>>(q, k, v, qbf, kbf, vbf, NPACK);

  transpose_cvt4<<<dim3(16, 16, 4), 256, 0, stream>>>(
      Wq, Wk, Wv, Wo, WtQ, WtK, WtV, WtO);

  gemm_qkv<<<dim3(8, 64, 3), 256, 0, stream>>>(
      qbf, kbf, vbf, WtQ, WtK, WtV, bq, bk, bv, Qb, Kb, Vtb);

  attn8<<<dim3(16, 64), 256, 0, stream>>>(Qb, Kb, Vtb, attn, AO);

  gemm_o<<<dim3(8, 64), 256, 0, stream>>>(AO, WtO, bo, tmpb);
  ln_kernel<<<dim3(8192), 256, 0, stream>>>(tmpb, q, gamma, beta, out0);
}

// Round 13
// 453.948 us; speedup vs baseline: 1.1824x; 1.0158x over previous
//
#include <hip/hip_runtime.h>
#include <stdint.h>

typedef unsigned short u16;
typedef unsigned int   u32;
typedef __attribute__((ext_vector_type(8))) short bf16x8;
typedef __attribute__((ext_vector_type(4))) float f32x4;
typedef __attribute__((ext_vector_type(4))) u32   u32x4;
typedef __attribute__((ext_vector_type(2))) u32   u32x2;

// Problem constants
#define BB 4
#define SS 2048
#define DD 1024
#define HH 16
// DK = DV = 64
// fold 1/sqrt(DK) * log2(e) into Q so attn softmax uses exp2 directly
#define QSCALE 0.18033688011112042f

__device__ __forceinline__ u16 f2b(float f){
  u32 u = __builtin_bit_cast(u32, f);
  u32 r = (u + 0x7FFFu + ((u >> 16) & 1u)) >> 16;   // RNE bf16 (finite values only)
  return (u16)r;
}
__device__ __forceinline__ float b2f(u16 h){
  return __builtin_bit_cast(float, (u32)h << 16);
}
__device__ __forceinline__ u32 cvtpk(float lo, float hi){
  u32 r; asm("v_cvt_pk_bf16_f32 %0, %1, %2" : "=v"(r) : "v"(lo), "v"(hi)); return r;
}

// async global->LDS, 16B per lane; lds base must be wave-uniform + lane*16.
__device__ __forceinline__ void gload16(const u16* g, u16* l){
  __builtin_amdgcn_global_load_lds(
      (const __attribute__((address_space(1))) void*)(uintptr_t)g,
      (__attribute__((address_space(3))) void*)(uintptr_t)l,
      16, 0, 0);
}

// ---------------- f32 -> bf16 bulk convert, 3 tensors in one launch -----------------
__global__ __launch_bounds__(256)
void cvt_bf16_3(const float* __restrict__ q, const float* __restrict__ k,
                const float* __restrict__ v, u16* __restrict__ qo,
                u16* __restrict__ ko, u16* __restrict__ vo, int npack)
{
  const float* in = blockIdx.y == 0 ? q : (blockIdx.y == 1 ? k : v);
  u16* out        = blockIdx.y == 0 ? qo : (blockIdx.y == 1 ? ko : vo);
  for(int i = blockIdx.x * 256 + threadIdx.x; i < npack; i += gridDim.x * 256){
    const float4* p = (const float4*)in + 2 * (size_t)i;
    float4 a = p[0], b = p[1];
    u32x4 o;
    o.x = f2b(a.x) | ((u32)f2b(a.y) << 16);
    o.y = f2b(a.z) | ((u32)f2b(a.w) << 16);
    o.z = f2b(b.x) | ((u32)f2b(b.y) << 16);
    o.w = f2b(b.z) | ((u32)f2b(b.w) << 16);
    ((u32x4*)out)[i] = o;
  }
}

// ---------------- weight transpose + bf16 convert, 64x64 tiles, full-line stores ----
__global__ __launch_bounds__(256)
void transpose_cvt4(const float* __restrict__ W0, const float* __restrict__ W1,
                    const float* __restrict__ W2, const float* __restrict__ W3,
                    u16* __restrict__ T0, u16* __restrict__ T1,
                    u16* __restrict__ T2, u16* __restrict__ T3)
{
  const float* W = blockIdx.z == 0 ? W0 : (blockIdx.z == 1 ? W1 : (blockIdx.z == 2 ? W2 : W3));
  u16*        Wt = blockIdx.z == 0 ? T0 : (blockIdx.z == 1 ? T1 : (blockIdx.z == 2 ? T2 : T3));
  __shared__ float tile[64][65];
  const int tid = threadIdx.x;
  const int n0 = blockIdx.x * 64, k0 = blockIdx.y * 64;
  const int lr = tid >> 4, lc = tid & 15;
  #pragma unroll
  for(int i = 0; i < 4; ++i){
    float4 v = *(const float4*)(W + (size_t)(k0 + lr + 16*i) * DD + n0 + lc * 4);
    tile[lr + 16*i][lc*4 + 0] = v.x;
    tile[lr + 16*i][lc*4 + 1] = v.y;
    tile[lr + 16*i][lc*4 + 2] = v.z;
    tile[lr + 16*i][lc*4 + 3] = v.w;
  }
  __syncthreads();
  // Wt[n0+row][k0+seg*8 .. +7] = tile[seg*8+j][row]
  #pragma unroll
  for(int j = 0; j < 2; ++j){
    int idx = j * 256 + tid;
    int row = idx >> 3, seg = idx & 7;
    u32x4 o;
    o.x = f2b(tile[seg*8+0][row]) | ((u32)f2b(tile[seg*8+1][row]) << 16);
    o.y = f2b(tile[seg*8+2][row]) | ((u32)f2b(tile[seg*8+3][row]) << 16);
    o.z = f2b(tile[seg*8+4][row]) | ((u32)f2b(tile[seg*8+5][row]) << 16);
    o.w = f2b(tile[seg*8+6][row]) | ((u32)f2b(tile[seg*8+7][row]) << 16);
    *(u32x4*)(Wt + (size_t)(n0 + row) * DD + k0 + seg * 8) = o;
  }
}

// ---- shared GEMM core: 128x128 tile, BK=64, XOR-swizzled LDS, K=1024 ---------------
// LDS tile [128 rows][8 granules of 8 bf16]; granule gr of row r stored at slot
// gr ^ (r&7) (pre-swizzled at the GLOBAL source; LDS dest linear per gload16 rule).
// Bank check: b128 read of granule (g^(r&7)) at row base+c16 -> 2-way alias = free.
#define GEMM_CORE(A_, Bt_)                                                             \
  f32x4 acc[4][4] = {};                                                                \
  for(int kt = 0; kt < 1024; kt += 64){                                                \
    __syncthreads();                                                                   \
    {                                                                                  \
      const int f0 = w * 4;                                                            \
      _Pragma("unroll")                                                                \
      for(int j = 0; j < 4; ++j){                                                      \
        int idx = (f0 + j) * 64 + ln;                                                  \
        int row = idx >> 3, s5 = idx & 7;                                              \
        int gcol = (s5 ^ (row & 7)) * 8;                                               \
        gload16(Bt_ + (size_t)(n0 + row) * 1024 + kt + gcol, Bs + (size_t)(f0+j)*512); \
        gload16(A_  + (size_t)(m0 + row) * 1024 + kt + gcol, As + (size_t)(f0+j)*512); \
      }                                                                                \
    }                                                                                  \
    __syncthreads();                                                                   \
    bf16x8 a0[4], a1[4], b0[4], b1[4];                                                 \
    _Pragma("unroll")                                                                  \
    for(int mi = 0; mi < 4; ++mi){                                                     \
      const int r = wr + mi*16 + c16;                                                  \
      a0[mi] = *(const bf16x8*)(As + r * 64 + ((g       ^ (r & 7)) << 3));             \
      a1[mi] = *(const bf16x8*)(As + r * 64 + (((4 + g) ^ (r & 7)) << 3));             \
    }                                                                                  \
    _Pragma("unroll")                                                                  \
    for(int ni = 0; ni < 4; ++ni){                                                     \
      const int r = wc + ni*16 + c16;                                                  \
      b0[ni] = *(const bf16x8*)(Bs + r * 64 + ((g       ^ (r & 7)) << 3));             \
      b1[ni] = *(const bf16x8*)(Bs + r * 64 + (((4 + g) ^ (r & 7)) << 3));             \
    }                                                                                  \
    _Pragma("unroll")                                                                  \
    for(int mi = 0; mi < 4; ++mi)                                                      \
      _Pragma("unroll")                                                                \
      for(int ni = 0; ni < 4; ++ni)                                                    \
        acc[mi][ni] = __builtin_amdgcn_mfma_f32_16x16x32_bf16(a0[mi], b0[ni], acc[mi][ni], 0, 0, 0); \
    _Pragma("unroll")                                                                  \
    for(int mi = 0; mi < 4; ++mi)                                                      \
      _Pragma("unroll")                                                                \
      for(int ni = 0; ni < 4; ++ni)                                                    \
        acc[mi][ni] = __builtin_amdgcn_mfma_f32_16x16x32_bf16(a1[mi], b1[ni], acc[mi][ni], 0, 0, 0); \
  }                                                                                    \
  __syncthreads();

// ---------------- merged QKV GEMM (blockIdx.z = mode), full-line LDS epilogue -------
__global__ __launch_bounds__(256)
void gemm_qkv(const u16* __restrict__ qA, const u16* __restrict__ kA, const u16* __restrict__ vA,
              const u16* __restrict__ BtQ, const u16* __restrict__ BtK, const u16* __restrict__ BtV,
              const float* __restrict__ bq, const float* __restrict__ bk, const float* __restrict__ bv,
              u16* __restrict__ Qo, u16* __restrict__ Ko, u16* __restrict__ Vo)
{
  const int mode = blockIdx.z;
  const u16* A   = mode == 0 ? qA  : (mode == 1 ? kA  : vA);
  const u16* Bt  = mode == 0 ? BtQ : (mode == 1 ? BtK : BtV);
  const float* bias = mode == 0 ? bq : (mode == 1 ? bk : bv);
  u16* Cout      = mode == 0 ? Qo  : (mode == 1 ? Ko  : Vo);

  __shared__ __align__(16) u16 smem[16384];       // 32KB: As 16KB + Bs 16KB; epilogue reuses
  u16* As = smem;                                 // [128][64] swizzled granules
  u16* Bs = smem + 128*64;
  const int tid = threadIdx.x;
  const int w = tid >> 6, ln = tid & 63, g = ln >> 4, c16 = ln & 15;
  const int m0 = blockIdx.y * 128, n0 = blockIdx.x * 128;
  const int wr = (w >> 1) * 64, wc = (w & 1) * 64;

  GEMM_CORE(A, Bt)

  char* st = (char*)smem + w * 8192;   // per-wave [64 rows][128B], XOR-swizzled 16B slots
  const float sc = (mode == 0) ? QSCALE : 1.f;
  const int bb = m0 >> 11;
  const int h  = (n0 + wc) >> 6;
  const int sbase = (m0 + wr) & 2047;

  if(mode < 2){
    #pragma unroll
    for(int ni = 0; ni < 4; ++ni){
      const float bvv = bias[n0 + wc + ni*16 + c16];
      const int gr = ni*2 + (c16 >> 3);
      const int within = (c16 & 7) * 2;
      #pragma unroll
      for(int mi = 0; mi < 4; ++mi)
        #pragma unroll
        for(int e = 0; e < 4; ++e){
          const int row = mi*16 + g*4 + e;
          *(u16*)(st + row*128 + ((gr ^ (row & 7)) << 4) + within)
              = f2b((acc[mi][ni][e] + bvv) * sc);
        }
    }
    asm volatile("s_waitcnt lgkmcnt(0)" ::: "memory");
    const int r8 = ln >> 3, jl = ln & 7;
    #pragma unroll
    for(int ii = 0; ii < 8; ++ii){
      const int row = ii*8 + r8;
      u16* dst = Cout + (((size_t)(bb*HH + h) * SS) + sbase + row) * 64 + jl*8;
      *(u32x4*)dst = *(const u32x4*)(st + row*128 + ((jl ^ (row & 7)) << 4));
    }
  } else {
    #pragma unroll
    for(int ni = 0; ni < 4; ++ni){
      const float bvv = bias[n0 + wc + ni*16 + c16];
      const int row = ni*16 + c16;      // d-local
      #pragma unroll
      for(int mi = 0; mi < 4; ++mi)
        #pragma unroll
        for(int e = 0; e < 4; ++e){
          const int sl = mi*16 + g*4 + e;   // s-local
          const int gr = sl >> 3;
          *(u16*)(st + row*128 + ((gr ^ (row & 7)) << 4) + (sl & 7) * 2)
              = f2b(acc[mi][ni][e] + bvv);
        }
    }
    asm volatile("s_waitcnt lgkmcnt(0)" ::: "memory");
    const int r8 = ln >> 3, jl = ln & 7;
    #pragma unroll
    for(int ii = 0; ii < 8; ++ii){
      const int d = ii*8 + r8;
      u16* dst = Cout + ((size_t)(bb*HH + h) * 64 + (n0 + wc - ((n0+wc)>>6<<6)) + d) * SS + sbase + jl*8;
      *(u32x4*)dst = *(const u32x4*)(st + d*128 + ((jl ^ (d & 7)) << 4));
    }
  }
}

// ---------------- out-proj GEMM -> bf16 tmp, full-line LDS epilogue -----------------
__global__ __launch_bounds__(256)
void gemm_o(const u16* __restrict__ A, const u16* __restrict__ Bt,
            const float* __restrict__ bias, u16* __restrict__ Cout)
{
  __shared__ __align__(16) u16 smem[16384];
  u16* As = smem;
  u16* Bs = smem + 128*64;
  const int tid = threadIdx.x;
  const int w = tid >> 6, ln = tid & 63, g = ln >> 4, c16 = ln & 15;
  const int m0 = blockIdx.y * 128, n0 = blockIdx.x * 128;
  const int wr = (w >> 1) * 64, wc = (w & 1) * 64;

  GEMM_CORE(A, Bt)

  char* st = (char*)smem + w * 8192;   // per-wave [64 rows][64 bf16 = 128B] swizzled
  #pragma unroll
  for(int ni = 0; ni < 4; ++ni){
    const float bvv = bias[n0 + wc + ni*16 + c16];
    const int gr = ni*2 + (c16 >> 3);
    const int within = (c16 & 7) * 2;
    #pragma unroll
    for(int mi = 0; mi < 4; ++mi)
      #pragma unroll
      for(int e = 0; e < 4; ++e){
        const int row = mi*16 + g*4 + e;
        *(u16*)(st + row*128 + ((gr ^ (row & 7)) << 4) + within)
            = f2b(acc[mi][ni][e] + bvv);
      }
  }
  asm volatile("s_waitcnt lgkmcnt(0)" ::: "memory");
  const int r8 = ln >> 3, jl = ln & 7;
  #pragma unroll
  for(int ii = 0; ii < 8; ++ii){
    const int row = ii*8 + r8;
    u16* dst = Cout + (size_t)(m0 + wr + row) * 1024 + n0 + wc + jl*8;
    *(u32x4*)dst = *(const u32x4*)(st + row*128 + ((jl ^ (row & 7)) << 4));
  }
}

// ---------------- fused attention v8 (round-10/12 verbatim, known-best) -------------
__global__ __launch_bounds__(256)
void attn8(const u16* __restrict__ Qb, const u16* __restrict__ Kb,
           const u16* __restrict__ Vt, float* __restrict__ attn_out,
           u16* __restrict__ AO)
{
  __shared__ __align__(16) u16 shm[32768];        // 64 KB
  const int tid = threadIdx.x, w = tid >> 6, ln = tid & 63, g = ln >> 4, c = ln & 15;
  const int bh = blockIdx.y;
  const int q0 = blockIdx.x * 128 + w * 32;

  const u16* Qp = Qb + ((size_t)bh * SS + q0) * 64;
  const u16* Kp = Kb + (size_t)bh * SS * 64;
  const u16* Vp = Vt + (size_t)bh * 64 * SS;

  const bf16x8 bq00 = *(const bf16x8*)(Qp + c * 64 + g * 8);
  const bf16x8 bq01 = *(const bf16x8*)(Qp + c * 64 + 32 + g * 8);
  const bf16x8 bq10 = *(const bf16x8*)(Qp + (16 + c) * 64 + g * 8);
  const bf16x8 bq11 = *(const bf16x8*)(Qp + (16 + c) * 64 + 32 + g * 8);

  auto stageK = [&](int slot, int t){
    const u16* src = Kp + (size_t)t * 64 * 64;
    #pragma unroll
    for(int j = 0; j < 2; ++j){
      int idx = j * 256 + tid;
      int r = idx >> 3, s5 = idx & 7;
      gload16(src + r * 64 + (((s5 ^ (r & 7))) << 3), shm + slot * 4096 + (idx << 3));
    }
  };
  auto stageV = [&](int slot, int t){
    #pragma unroll
    for(int j = 0; j < 2; ++j){
      int idx = j * 256 + tid;
      int r = idx >> 3, s5 = idx & 7;
      gload16(Vp + (size_t)r * SS + t * 64 + (((s5 ^ (r & 7))) << 3),
              shm + 12288 + slot * 4096 + (idx << 3));
    }
  };

  // ================= pass 1: denominators, 2 tiles per barrier =================
  float l0 = 0.f, l1 = 0.f;
  auto comp1 = [&](const u16* kb_){
    f32x4 s[2][4] = {};
    #pragma unroll
    for(int ch = 0; ch < 4; ++ch){
      const int r = ch * 16 + c;
      bf16x8 ka0 = *(const bf16x8*)(kb_ + r * 64 + ((g       ^ (c & 7)) << 3));
      bf16x8 ka1 = *(const bf16x8*)(kb_ + r * 64 + (((4 + g) ^ (c & 7)) << 3));
      s[0][ch] = __builtin_amdgcn_mfma_f32_16x16x32_bf16(ka0, bq00, s[0][ch], 0, 0, 0);
      s[0][ch] = __builtin_amdgcn_mfma_f32_16x16x32_bf16(ka1, bq01, s[0][ch], 0, 0, 0);
      s[1][ch] = __builtin_amdgcn_mfma_f32_16x16x32_bf16(ka0, bq10, s[1][ch], 0, 0, 0);
      s[1][ch] = __builtin_amdgcn_mfma_f32_16x16x32_bf16(ka1, bq11, s[1][ch], 0, 0, 0);
    }
    #pragma unroll
    for(int ch = 0; ch < 4; ++ch)
      #pragma unroll
      for(int e = 0; e < 4; ++e){
        l0 += __builtin_amdgcn_exp2f(s[0][ch][e]);
        l1 += __builtin_amdgcn_exp2f(s[1][ch][e]);
      }
  };

  stageK(0, 0); stageK(1, 1);
  asm volatile("s_waitcnt vmcnt(2)" ::: "memory");
  __builtin_amdgcn_s_barrier();
  for(int t = 0; t < 32; t += 2){
    if(t < 30){ stageK((t + 2) & 3, t + 2); stageK((t + 3) & 3, t + 3); }
    __builtin_amdgcn_sched_barrier(0);
    comp1(shm + (t & 3) * 4096);
    if(t < 30) asm volatile("s_waitcnt vmcnt(4)" ::: "memory");
    else       asm volatile("s_waitcnt vmcnt(0)" ::: "memory");
    __builtin_amdgcn_sched_barrier(0);
    comp1(shm + ((t + 1) & 3) * 4096);
    if(t < 30) asm volatile("s_waitcnt vmcnt(2)" ::: "memory");
    __builtin_amdgcn_s_barrier();
  }
  l0 += __shfl_xor(l0, 16, 64); l0 += __shfl_xor(l0, 32, 64);
  l1 += __shfl_xor(l1, 16, 64); l1 += __shfl_xor(l1, 32, 64);
  const float rl0 = 1.f / l0, rl1 = 1.f / l1;

  // ================= pass 2: recompute + write attn + PV =================
  f32x4 acc[2][4] = {};
  float* aout = attn_out + ((size_t)bh * SS + q0) * SS;
  u16* pw0 = shm + 24576 + w * 2048;
  u16* pw1 = pw0 + 1024;

  stageK(0, 0); stageV(0, 0); stageK(1, 1); stageV(1, 1);
  asm volatile("s_waitcnt vmcnt(4)" ::: "memory");
  __builtin_amdgcn_s_barrier();

  for(int t = 0; t < 32; ++t){
    if(t < 30){ stageK((t + 2) % 3, t + 2); stageV((t + 2) % 3, t + 2); }
    __builtin_amdgcn_sched_barrier(0);
    const int kv0 = t * 64;
    const u16* kb_ = shm + (t % 3) * 4096;
    const u16* vb_ = shm + 12288 + (t % 3) * 4096;

    f32x4 s[2][4] = {};
    __builtin_amdgcn_s_setprio(1);
    #pragma unroll
    for(int ch = 0; ch < 4; ++ch){
      const int r = ch * 16 + c;
      bf16x8 ka0 = *(const bf16x8*)(kb_ + r * 64 + ((g       ^ (c & 7)) << 3));
      bf16x8 ka1 = *(const bf16x8*)(kb_ + r * 64 + (((4 + g) ^ (c & 7)) << 3));
      s[0][ch] = __builtin_amdgcn_mfma_f32_16x16x32_bf16(ka0, bq00, s[0][ch], 0, 0, 0);
      s[0][ch] = __builtin_amdgcn_mfma_f32_16x16x32_bf16(ka1, bq01, s[0][ch], 0, 0, 0);
      s[1][ch] = __builtin_amdgcn_mfma_f32_16x16x32_bf16(ka0, bq10, s[1][ch], 0, 0, 0);
      s[1][ch] = __builtin_amdgcn_mfma_f32_16x16x32_bf16(ka1, bq11, s[1][ch], 0, 0, 0);
    }
    __builtin_amdgcn_s_setprio(0);

    #pragma unroll
    for(int qb = 0; qb < 2; ++qb){
      const float rl = qb ? rl1 : rl0;
      u16* pw = qb ? pw1 : pw0;
      #pragma unroll
      for(int ch = 0; ch < 4; ++ch){
        float p0 = __builtin_amdgcn_exp2f(s[qb][ch][0]) * rl;
        float p1 = __builtin_amdgcn_exp2f(s[qb][ch][1]) * rl;
        float p2 = __builtin_amdgcn_exp2f(s[qb][ch][2]) * rl;
        float p3 = __builtin_amdgcn_exp2f(s[qb][ch][3]) * rl;
        u32x2 pk2 = { cvtpk(p0, p1), cvtpk(p2, p3) };
        *(u32x2*)((char*)pw + c * 128 + (((ch * 2 + (g >> 1)) ^ (c & 7)) << 4) + ((g & 1) << 3)) = pk2;
      }
    }
    asm volatile("s_waitcnt lgkmcnt(0)" ::: "memory");
    __builtin_amdgcn_sched_barrier(0);

    __builtin_amdgcn_s_setprio(1);
    #pragma unroll
    for(int kc = 0; kc < 2; ++kc){
      bf16x8 ap0 = *(const bf16x8*)((const char*)pw0 + c * 128 + (((kc * 4 + g) ^ (c & 7)) << 4));
      bf16x8 ap1 = *(const bf16x8*)((const char*)pw1 + c * 128 + (((kc * 4 + g) ^ (c & 7)) << 4));
      #pragma unroll
      for(int ni = 0; ni < 4; ++ni){
        bf16x8 bv = *(const bf16x8*)(vb_ + (ni * 16 + c) * 64 + (((kc * 4 + g) ^ (c & 7)) << 3));
        acc[0][ni] = __builtin_amdgcn_mfma_f32_16x16x32_bf16(ap0, bv, acc[0][ni], 0, 0, 0);
        acc[1][ni] = __builtin_amdgcn_mfma_f32_16x16x32_bf16(ap1, bv, acc[1][ni], 0, 0, 0);
      }
    }
    __builtin_amdgcn_s_setprio(0);

    // ---- attn write phase: FULL-LINE stores from pbuf (8 rows x 128B per instr)
    {
      const int r8 = ln >> 3;
      const int jl = ln & 7;
      #pragma unroll
      for(int qb = 0; qb < 2; ++qb){
        const u16* pw = qb ? pw1 : pw0;
        #pragma unroll
        for(int rh = 0; rh < 2; ++rh){
          const int r = rh * 8 + r8;
          #pragma unroll
          for(int chf = 0; chf < 2; ++chf){
            const int jg = chf * 8 + jl;
            const int ch2 = jg >> 2, g2 = jg & 3;
            const int slot = ch2 * 2 + (g2 >> 1);
            u32x2 pk = *(const u32x2*)((const char*)pw + r * 128 +
                         (((slot ^ (r & 7))) << 4) + ((g2 & 1) << 3));
            f32x4 o;
            o[0] = b2f((u16)(pk.x & 0xFFFFu)); o[1] = b2f((u16)(pk.x >> 16));
            o[2] = b2f((u16)(pk.y & 0xFFFFu)); o[3] = b2f((u16)(pk.y >> 16));
            *(f32x4*)(aout + (size_t)(qb * 16 + r) * SS + kv0 + jg * 4) = o;
          }
        }
      }
    }

    if(t == 0)       asm volatile("s_waitcnt vmcnt(12)" ::: "memory");
    else if(t < 30)  asm volatile("s_waitcnt vmcnt(20)" ::: "memory");
    else if(t == 30) asm volatile("s_waitcnt vmcnt(16)" ::: "memory");
    __builtin_amdgcn_s_barrier();
  }

  // ---- AO epilogue
  u16* aos = pw0;   // [32][64] u16 = 2048, spans pw0+pw1
  #pragma unroll
  for(int qb = 0; qb < 2; ++qb)
    #pragma unroll
    for(int ni = 0; ni < 4; ++ni)
      #pragma unroll
      for(int e = 0; e < 4; ++e)
        aos[(qb * 16 + 4 * g + e) * 64 + ni * 16 + c] = f2b(acc[qb][ni][e]);
  asm volatile("s_waitcnt lgkmcnt(0)" ::: "memory");
  __builtin_amdgcn_sched_barrier(0);
  {
    const int bb = bh >> 4, h = bh & 15;
    #pragma unroll
    for(int p2 = 0; p2 < 4; ++p2){
      int idx = p2 * 64 + ln;
      int row = idx >> 3, col16 = (idx & 7) * 8;
      u16* dst = AO + ((size_t)bb * SS + q0 + row) * 1024 + h * 64 + col16;
      *(u32x4*)dst = *(const u32x4*)(aos + row * 64 + col16);
    }
  }
}

// ---------------- residual + LayerNorm: wave-per-row, no barriers -------------------
__global__ __launch_bounds__(256)
void ln_kernel(const u16* __restrict__ tmpb, const float* __restrict__ qin,
               const float* __restrict__ gamma, const float* __restrict__ beta,
               float* __restrict__ out)
{
  const int tid = threadIdx.x, w = tid >> 6, ln = tid & 63;
  const int row = blockIdx.x * 4 + w;
  const u16*   tp = tmpb + (size_t)row * 1024;
  const float* qp = qin  + (size_t)row * 1024;
  float xs[16];
  float s = 0.f, s2 = 0.f;
  #pragma unroll
  for(int ck = 0; ck < 4; ++ck){
    const int col = ck * 256 + ln * 4;
    const uint2 tv = *(const uint2*)(tp + col);
    const float4 q4 = *(const float4*)(qp + col);
    float x0 = b2f((u16)(tv.x & 0xFFFFu)) + q4.x;
    float x1 = b2f((u16)(tv.x >> 16))     + q4.y;
    float x2 = b2f((u16)(tv.y & 0xFFFFu)) + q4.z;
    float x3 = b2f((u16)(tv.y >> 16))     + q4.w;
    xs[ck*4+0] = x0; xs[ck*4+1] = x1; xs[ck*4+2] = x2; xs[ck*4+3] = x3;
    s  += x0 + x1 + x2 + x3;
    s2 += x0*x0 + x1*x1 + x2*x2 + x3*x3;
  }
  #pragma unroll
  for(int m = 1; m < 64; m <<= 1){
    s  += __shfl_xor(s,  m, 64);
    s2 += __shfl_xor(s2, m, 64);
  }
  const float mu   = s * (1.f / 1024.f);
  const float var  = s2 * (1.f / 1024.f) - mu * mu;
  const float rstd = rsqrtf(var + 1e-5f);
  #pragma unroll
  for(int ck = 0; ck < 4; ++ck){
    const int col = ck * 256 + ln * 4;
    const float4 g4 = *(const float4*)(gamma + col);
    const float4 b4 = *(const float4*)(beta + col);
    float4 o;
    o.x = (xs[ck*4+0] - mu) * rstd * g4.x + b4.x;
    o.y = (xs[ck*4+1] - mu) * rstd * g4.y + b4.y;
    o.z = (xs[ck*4+2] - mu) * rstd * g4.z + b4.z;
    o.w = (xs[ck*4+3] - mu) * rstd * g4.w + b4.w;
    *(float4*)(out + (size_t)row * 1024 + col) = o;
  }
}

// ------------------------------------------------------------------------------------
extern "C" void kernel_launch(void* const* d_in, const int* in_sizes, int n_in,
                              void* d_out, int out_size, void* d_ws, size_t ws_size,
                              hipStream_t stream)
{
  (void)in_sizes; (void)n_in; (void)out_size; (void)ws_size;
  const float* q     = (const float*)d_in[0];
  const float* k     = (const float*)d_in[1];
  const float* v     = (const float*)d_in[2];
  const float* Wq    = (const float*)d_in[3];
  const float* bq    = (const float*)d_in[4];
  const float* Wk    = (const float*)d_in[5];
  const float* bk    = (const float*)d_in[6];
  const float* Wv    = (const float*)d_in[7];
  const float* bv    = (const float*)d_in[8];
  const float* Wo    = (const float*)d_in[9];
  const float* bo    = (const float*)d_in[10];
  const float* gamma = (const float*)d_in[11];
  const float* beta  = (const float*)d_in[12];

  char* p = (char*)d_ws;
  auto alloc = [&](size_t bytes) -> void* {
    void* r = (void*)p; p += (bytes + 255) & ~(size_t)255; return r;
  };
  const size_t NTOK = (size_t)BB * SS;           // 8192
  u16* WtQ  = (u16*)alloc((size_t)DD * DD * 2);
  u16* WtK  = (u16*)alloc((size_t)DD * DD * 2);
  u16* WtV  = (u16*)alloc((size_t)DD * DD * 2);
  u16* WtO  = (u16*)alloc((size_t)DD * DD * 2);
  u16* Qb   = (u16*)alloc(NTOK * DD * 2);
  u16* Kb   = (u16*)alloc(NTOK * DD * 2);
  u16* Vtb  = (u16*)alloc(NTOK * DD * 2);
  u16* AO   = (u16*)alloc(NTOK * DD * 2);
  u16* qbf  = (u16*)alloc(NTOK * DD * 2);
  u16* kbf  = (u16*)alloc(NTOK * DD * 2);
  u16* vbf  = (u16*)alloc(NTOK * DD * 2);
  u16* tmpb = (u16*)alloc(NTOK * DD * 2);

  float* out0 = (float*)d_out;
  float* attn = out0 + NTOK * DD;                // [B,H,S,S]

  const int NPACK = (int)(NTOK * DD / 8);        // 1,048,576 packs of 8
  cvt_bf16_3<<<dim3(1024, 3), 256, 0, stream>>>(q, k, v, qbf, kbf, vbf, NPACK);

  transpose_cvt4<<<dim3(16, 16, 4), 256, 0, stream>>>(
      Wq, Wk, Wv, Wo, WtQ, WtK, WtV, WtO);

  gemm_qkv<<<dim3(8, 64, 3), 256, 0, stream>>>(
      qbf, kbf, vbf, WtQ, WtK, WtV, bq, bk, bv, Qb, Kb, Vtb);

  attn8<<<dim3(16, 64), 256, 0, stream>>>(Qb, Kb, Vtb, attn, AO);

  gemm_o<<<dim3(8, 64), 256, 0, stream>>>(AO, WtO, bo, tmpb);
  ln_kernel<<<dim3(2048), 256, 0, stream>>>(tmpb, q, gamma, beta, out0);
}